// Round 1
// baseline (4906.844 us; speedup 1.0000x reference)
//
#include <hip/hip_runtime.h>

// Problem constants (match reference setup_inputs)
#define C 32
#define NNODES 50000
#define NEDGES 1600000

// One thread per (edge, channel). c is the fast dimension so all 32 lanes of a
// half-wave share the same edge's i/j indices (L1 broadcast).
// x  : [C, N] float32
// x1 : [C, N] accumulator for scatter(+g at iInd)  (= d_out first half)
// x2 : [C, N] accumulator for scatter(+g at jInd)  (= d_out second half)
__global__ void scatter_kernel(const float* __restrict__ x,
                               const int* __restrict__ iInd,
                               const int* __restrict__ jInd,
                               float* __restrict__ x1,
                               float* __restrict__ x2,
                               long long total) {
    long long t = (long long)blockIdx.x * blockDim.x + threadIdx.x;
    if (t >= total) return;
    int e = (int)(t >> 5);   // t / C  (C == 32)
    int c = (int)(t & 31);   // t % C
    int i = iInd[e];
    int j = jInd[e];
    size_t ci = (size_t)c * NNODES + (size_t)i;
    size_t cj = (size_t)c * NNODES + (size_t)j;
    float g = x[ci] - x[cj];
    atomicAdd(&x1[ci], g);
    atomicAdd(&x2[cj], g);
}

// lap = x1 - x2 ; ave = max(x1, x2), in place on d_out's two halves.
__global__ void finalize_kernel(float* __restrict__ out) {
    int k = blockIdx.x * blockDim.x + threadIdx.x;
    const int CN = C * NNODES;
    if (k >= CN) return;
    float a = out[k];
    float b = out[CN + k];
    out[k] = a - b;            // lap
    out[CN + k] = fmaxf(a, b); // ave
}

extern "C" void kernel_launch(void* const* d_in, const int* in_sizes, int n_in,
                              void* d_out, int out_size, void* d_ws, size_t ws_size,
                              hipStream_t stream) {
    const float* x    = (const float*)d_in[0];
    const int*   iInd = (const int*)d_in[1];
    const int*   jInd = (const int*)d_in[2];
    float* out = (float*)d_out;

    const int CN = C * NNODES;

    // Accumulators live directly in d_out; must zero them every call
    // (harness poisons once, never re-poisons between replays).
    hipMemsetAsync(out, 0, sizeof(float) * 2 * (size_t)CN, stream);

    float* x1 = out;        // scatter(+g at iInd)
    float* x2 = out + CN;   // scatter(+g at jInd)

    long long total = (long long)NEDGES * C;
    int block = 256;
    long long grid = (total + block - 1) / block;
    scatter_kernel<<<(int)grid, block, 0, stream>>>(x, iInd, jInd, x1, x2, total);

    finalize_kernel<<<(CN + 255) / 256, 256, 0, stream>>>(out);
}

// Round 2
// 346.799 us; speedup vs baseline: 14.1489x; 14.1489x over previous
//
#include <hip/hip_runtime.h>

// Problem constants (match reference setup_inputs)
#define C 32
#define NNODES 50000
#define NEDGES 1600000

// ---------- [N,C]-layout path (fast): ws = xT | x1T | x2T ----------

// Transpose x [C,N] -> xT [N,C] via LDS tile (256 nodes x 32 ch).
__global__ void transpose_x_kernel(const float* __restrict__ x,
                                   float* __restrict__ xT) {
    __shared__ float lds[32 * 257];
    int n0 = blockIdx.x * 256;
    int tid = threadIdx.x;
#pragma unroll
    for (int c = 0; c < 32; ++c) {
        int n = n0 + tid;
        lds[c * 257 + tid] = (n < NNODES) ? x[(size_t)c * NNODES + n] : 0.0f;
    }
    __syncthreads();
#pragma unroll
    for (int k = 0; k < 32; ++k) {
        int q = k * 256 + tid;      // 0..8191
        int nl = q >> 5;            // local node
        int c  = q & 31;            // channel
        int n = n0 + nl;
        if (n < NNODES) xT[(size_t)n * 32 + c] = lds[c * 257 + nl];
    }
}

// One thread per (edge, channel); channel fast -> each edge's 32 atomics
// cover 128 contiguous bytes (2 cache lines) in x1T/x2T.
__global__ void scatter_nc_kernel(const float* __restrict__ xT,
                                  const int* __restrict__ iInd,
                                  const int* __restrict__ jInd,
                                  float* __restrict__ x1T,
                                  float* __restrict__ x2T) {
    long long t = (long long)blockIdx.x * blockDim.x + threadIdx.x;
    if (t >= (long long)NEDGES * C) return;
    int e = (int)(t >> 5);
    int c = (int)(t & 31);
    int i = iInd[e];
    int j = jInd[e];
    size_t ii = (size_t)i * C + c;
    size_t jj = (size_t)j * C + c;
    float g = xT[ii] - xT[jj];
    atomicAdd(&x1T[ii], g);
    atomicAdd(&x2T[jj], g);
}

// Read x1T/x2T [N,C] coalesced, transpose via LDS (128 nodes x 32 ch),
// write lap = x1-x2 and ave = max(x1,x2) into out [2][C,N] coalesced.
__global__ void finalize_nc_kernel(const float* __restrict__ x1T,
                                   const float* __restrict__ x2T,
                                   float* __restrict__ out) {
    __shared__ float la[32 * 129];
    __shared__ float lb[32 * 129];
    int n0 = blockIdx.x * 128;
    int tid = threadIdx.x;
#pragma unroll
    for (int k = 0; k < 16; ++k) {
        int q = k * 256 + tid;      // 0..4095
        int nl = q >> 5;
        int c  = q & 31;
        int n = n0 + nl;
        float a = 0.0f, b = 0.0f;
        if (n < NNODES) {
            a = x1T[(size_t)n * C + c];
            b = x2T[(size_t)n * C + c];
        }
        la[c * 129 + nl] = a;
        lb[c * 129 + nl] = b;
    }
    __syncthreads();
    const size_t CN = (size_t)C * NNODES;
#pragma unroll
    for (int r = 0; r < 16; ++r) {
        int c  = r * 2 + (tid >> 7);
        int nl = tid & 127;
        int n = n0 + nl;
        if (n < NNODES) {
            float a = la[c * 129 + nl];
            float b = lb[c * 129 + nl];
            out[(size_t)c * NNODES + n] = a - b;           // lap
            out[CN + (size_t)c * NNODES + n] = fmaxf(a, b); // ave
        }
    }
}

// ---------- fallback [C,N] path (round-1, used only if ws too small) ----------

__global__ void scatter_cn_kernel(const float* __restrict__ x,
                                  const int* __restrict__ iInd,
                                  const int* __restrict__ jInd,
                                  float* __restrict__ x1,
                                  float* __restrict__ x2) {
    long long t = (long long)blockIdx.x * blockDim.x + threadIdx.x;
    if (t >= (long long)NEDGES * C) return;
    int e = (int)(t >> 5);
    int c = (int)(t & 31);
    int i = iInd[e];
    int j = jInd[e];
    size_t ci = (size_t)c * NNODES + (size_t)i;
    size_t cj = (size_t)c * NNODES + (size_t)j;
    float g = x[ci] - x[cj];
    atomicAdd(&x1[ci], g);
    atomicAdd(&x2[cj], g);
}

__global__ void finalize_cn_kernel(float* __restrict__ out) {
    int k = blockIdx.x * blockDim.x + threadIdx.x;
    const int CN = C * NNODES;
    if (k >= CN) return;
    float a = out[k];
    float b = out[CN + k];
    out[k] = a - b;
    out[CN + k] = fmaxf(a, b);
}

extern "C" void kernel_launch(void* const* d_in, const int* in_sizes, int n_in,
                              void* d_out, int out_size, void* d_ws, size_t ws_size,
                              hipStream_t stream) {
    const float* x    = (const float*)d_in[0];
    const int*   iInd = (const int*)d_in[1];
    const int*   jInd = (const int*)d_in[2];
    float* out = (float*)d_out;

    const size_t CN = (size_t)C * NNODES;
    const size_t need = 3 * CN * sizeof(float); // xT + x1T + x2T = 19.2 MB

    if (ws_size >= need) {
        float* xT  = (float*)d_ws;
        float* x1T = xT + CN;
        float* x2T = x1T + CN;

        transpose_x_kernel<<<(NNODES + 255) / 256, 256, 0, stream>>>(x, xT);
        hipMemsetAsync(x1T, 0, 2 * CN * sizeof(float), stream);

        long long total = (long long)NEDGES * C;
        int grid = (int)((total + 255) / 256);
        scatter_nc_kernel<<<grid, 256, 0, stream>>>(xT, iInd, jInd, x1T, x2T);

        finalize_nc_kernel<<<(NNODES + 127) / 128, 256, 0, stream>>>(x1T, x2T, out);
    } else {
        // Fallback: accumulate directly in d_out ([C,N] layout).
        hipMemsetAsync(out, 0, 2 * CN * sizeof(float), stream);
        float* x1 = out;
        float* x2 = out + CN;
        long long total = (long long)NEDGES * C;
        int grid = (int)((total + 255) / 256);
        scatter_cn_kernel<<<grid, 256, 0, stream>>>(x, iInd, jInd, x1, x2);
        finalize_cn_kernel<<<(int)((CN + 255) / 256), 256, 0, stream>>>(out);
    }
}